// Round 1
// baseline (456.602 us; speedup 1.0000x reference)
//
#include <hip/hip_runtime.h>
#include <math.h>

#define PI_D 3.14159265358979323846

// ---------------- workspace layout (float offsets) ----------------
// total = 25955328 floats = 103.9 MB
constexpr size_t OFF_P    = 0;                   // P[m][l][t]  256*256*256 (m>=0; zeros for l<m)
constexpr size_t OFF_FRE  = 16777216;            // F'[m][t][c] 256*256*32  (w folded in)
constexpr size_t OFF_FIM  = 18874368;
constexpr size_t OFF_SFRE = 20971520;            // flm[m][l][c] 256*256*32
constexpr size_t OFF_SFIM = 23068672;
constexpr size_t OFF_COS  = 25165824;            // fwd trig [phi][m] 511*256
constexpr size_t OFF_SIN  = 25296640;
constexpr size_t OFF_COSI = 25427456;            // inv trig [j][phi(512 pad)] 255*512
constexpr size_t OFF_SINI = 25558016;
constexpr size_t OFF_WPR  = 25688576;            // premult conv w [l][o][i] 128*32*32
constexpr size_t OFF_WPI  = 25819648;
constexpr size_t OFF_WQ   = 25950720;            // 256 quadrature weights
constexpr size_t OFF_TC   = 25950976;            // 256 (t_cplx re|im)
constexpr size_t OFF_WLW  = 25951232;            // 128*4 l-resize weights
constexpr size_t OFF_WLI  = 25951744;            // 128*4 l-resize indices (int)
constexpr size_t OFF_WMW  = 25952256;            // 255*6 m-resize weights (pad 1536)
constexpr size_t OFF_WMI  = 25953792;            // 255*6 m-resize indices (int)
// overlays (lifetimes disjoint):
constexpr size_t OFF_RRE  = OFF_FRE;             // resized flm [j'][l'][c] 255*128*32
constexpr size_t OFF_RIM  = OFF_FRE + 1044480;
constexpr size_t OFF_CRE  = OFF_FIM;             // conv out    [j][l][o]
constexpr size_t OFF_CIM  = OFF_FIM + 1044480;
constexpr size_t OFF_GRE  = OFF_SFRE;            // G [t][j][c] 256*255*32
constexpr size_t OFF_GIM  = OFF_SFRE + 2088960;

__device__ __forceinline__ float4 ld4(const float* p) { return *(const float4*)p; }

// ---------------- setup: quadrature, t_cplx, resize taps ----------------
__global__ void k_setup_small(const float* t_emb, const float* w_tr, const float* b_tr,
                              const float* w_ti, const float* b_ti, float* ws) {
  int tid = threadIdx.x;
  if (tid < 256) {
    double theta = PI_D * (2.0 * tid + 1.0) / 511.0;
    double dang = 2.0 * PI_D / 511.0;
    ws[OFF_WQ + tid] = (float)(sin(theta) * dang * dang);
  }
  if (tid < 128) {
    // t_cplx
    float sr = b_tr[tid], si = b_ti[tid];
    for (int T = 0; T < 256; ++T) {
      float e = t_emb[T];
      sr += e * w_tr[T * 128 + tid];
      si += e * w_ti[T * 128 + tid];
    }
    ws[OFF_TC + tid] = sr;
    ws[OFF_TC + 128 + tid] = si;
    // l-dim resize taps: in 256 -> out 128, scale 0.5, kernel_scale 2 (antialias)
    double sf = 2.0 * tid + 0.5;
    double wv[4]; int iv[4]; double wsum = 0.0;
    for (int a = 0; a < 4; ++a) {
      int t = 2 * tid - 1 + a;
      double r = 1.0 - fabs(sf - (double)t) * 0.5;
      bool valid = (t >= 0 && t < 256 && r > 0.0);
      wv[a] = valid ? r : 0.0; iv[a] = valid ? t : 0;
      wsum += wv[a];
    }
    for (int a = 0; a < 4; ++a) {
      ws[OFF_WLW + tid * 4 + a] = (float)(wv[a] / wsum);
      ((int*)(ws + OFF_WLI))[tid * 4 + a] = iv[a];
    }
  }
  if (tid < 255) {
    // m-dim resize taps: in 511 -> out 255
    double inv = 511.0 / 255.0;
    double sf = (tid + 0.5) * inv - 0.5;
    int t0 = (int)floor(sf) - 2;
    double wv[6]; int iv[6]; double wsum = 0.0;
    for (int b = 0; b < 6; ++b) {
      int t = t0 + b;
      double r = 1.0 - fabs(sf - (double)t) * (255.0 / 511.0);
      bool valid = (t >= 0 && t < 511 && r > 0.0);
      wv[b] = valid ? r : 0.0; iv[b] = valid ? t : 0;
      wsum += wv[b];
    }
    for (int b = 0; b < 6; ++b) {
      ws[OFF_WMW + tid * 6 + b] = (float)(wv[b] / wsum);
      ((int*)(ws + OFF_WMI))[tid * 6 + b] = iv[b];
    }
  }
}

// ---------------- trig tables ----------------
__global__ void k_trig_fwd(float* ws) {   // grid 511 x 256
  int gid = blockIdx.x * 256 + threadIdx.x;       // < 511*256
  int phi = gid >> 8, m = gid & 255;
  int k = (m * phi) % 511;
  double ang = (2.0 * PI_D / 511.0) * (double)k;
  ws[OFF_COS + gid] = (float)cos(ang);
  ws[OFF_SIN + gid] = (float)sin(ang);
}

__global__ void k_trig_inv(float* ws) {   // grid 510 x 256 -> 255*512
  int gid = blockIdx.x * 256 + threadIdx.x;
  int j = gid >> 9, p = gid & 511;
  float cv = 0.f, sv = 0.f;
  if (p < 511) {
    int m = j - 127;
    int k = ((m * p) % 511 + 511) % 511;
    double ang = (2.0 * PI_D / 511.0) * (double)k;
    cv = (float)cos(ang); sv = (float)sin(ang);
  }
  ws[OFF_COSI + gid] = cv;
  ws[OFF_SINI + gid] = sv;
}

// ---------------- premultiplied conv weights, transposed [l][o][i] ----------------
__global__ void k_wprep(const float* wr_, const float* wi_, float* ws) { // grid 512 x 256
  int gid = blockIdx.x * 256 + threadIdx.x;       // < 131072
  int l = gid >> 10, rem = gid & 1023, o = rem >> 5, i = rem & 31;
  float wr = wr_[(l << 10) + i * 32 + o];
  float wi = wi_[(l << 10) + i * 32 + o];
  float tcr = ws[OFF_TC + l], tci = ws[OFF_TC + 128 + l];
  ws[OFF_WPR + gid] = tcr * wr - tci * wi;
  ws[OFF_WPI + gid] = tcr * wi + tci * wr;
}

// ---------------- Legendre basis (fp64 recurrence, matches numpy) ----------------
__global__ void k_legendre(float* ws) {   // grid 256 (m) x 256 (t)
  int m = blockIdx.x, t = threadIdx.x;
  double theta = PI_D * (2.0 * t + 1.0) / 511.0;
  double ct = cos(theta), st = sin(theta);
  float* Pm = ws + OFF_P + (size_t)m * 65536 + t;
  double p0 = sqrt(1.0 / (4.0 * PI_D));
  for (int k = 1; k <= m; ++k) p0 *= -sqrt((2.0 * k + 1.0) / (2.0 * k)) * st;
  for (int l = 0; l < m; ++l) Pm[(size_t)l * 256] = 0.f;
  Pm[(size_t)m * 256] = (float)p0;
  if (m + 1 < 256) {
    double p1 = sqrt(2.0 * m + 3.0) * ct * p0;
    Pm[(size_t)(m + 1) * 256] = (float)p1;
    for (int l = m + 2; l < 256; ++l) {
      double ll = l, mm = m;
      double den = ll * ll - mm * mm;
      double a = sqrt((4.0 * ll * ll - 1.0) / den);
      double b = sqrt((2.0 * ll + 1.0) * (ll - 1.0 - mm) * (ll - 1.0 + mm) / ((2.0 * ll - 3.0) * den));
      double p2 = a * ct * p1 - b * p0;
      Pm[(size_t)l * 256] = (float)p2;
      p0 = p1; p1 = p2;
    }
  }
}

// ---------------- forward DFT over phi (m = 0..255 only, Hermitian) ----------------
#define DFT_PADS 132
__global__ __launch_bounds__(128) void k_dft(const float* x, float* ws) { // grid 512
  int bx = blockIdx.x;
  int t = bx >> 1, m_base = (bx & 1) << 7;
  int tid = threadIdx.x;
  int slot = tid >> 2, cg = tid & 3;  // slot 0..31 (4 consecutive m each), cg 0..3 (8 c each)
  int m0 = m_base + slot * 4;
  int c0 = cg * 8;
  __shared__ __align__(16) float cosl[32 * DFT_PADS];
  __shared__ __align__(16) float sinl[32 * DFT_PADS];
  __shared__ __align__(16) float xl[32 * 32];
  float accr[4][8], acci[4][8];
#pragma unroll
  for (int a = 0; a < 4; ++a)
#pragma unroll
    for (int q = 0; q < 8; ++q) { accr[a][q] = 0.f; acci[a][q] = 0.f; }
  const float* COSg = ws + OFF_COS;
  const float* SINg = ws + OFF_SIN;
  for (int ch = 0; ch < 16; ++ch) {
    int phi0 = ch * 32;
    __syncthreads();
    // trig tile [32 p][128 m] -> lds [p][DFT_PADS]
#pragma unroll
    for (int r = 0; r < 8; ++r) {
      int idx4 = tid + 128 * r;       // 0..1023
      int p = idx4 >> 5, m4 = (idx4 & 31) * 4;
      int phi = phi0 + p;
      float4 cv = make_float4(0.f, 0.f, 0.f, 0.f), sv = make_float4(0.f, 0.f, 0.f, 0.f);
      if (phi < 511) {
        cv = ld4(COSg + (size_t)phi * 256 + m_base + m4);
        sv = ld4(SINg + (size_t)phi * 256 + m_base + m4);
      }
      float* cd = cosl + p * DFT_PADS + m4;
      float* sd = sinl + p * DFT_PADS + m4;
      cd[0] = cv.x; cd[1] = cv.y; cd[2] = cv.z; cd[3] = cv.w;
      sd[0] = sv.x; sd[1] = sv.y; sd[2] = sv.z; sd[3] = sv.w;
    }
    // x tile [32 p][32 c]
#pragma unroll
    for (int r = 0; r < 2; ++r) {
      int idx4 = tid + 128 * r;       // 0..255
      int p = idx4 >> 3, c4 = (idx4 & 7) * 4;
      int phi = phi0 + p;
      float4 xv = make_float4(0.f, 0.f, 0.f, 0.f);
      if (phi < 511) xv = ld4(x + ((size_t)t * 511 + phi) * 32 + c4);
      *(float4*)(xl + p * 32 + c4) = xv;
    }
    __syncthreads();
    for (int p = 0; p < 32; ++p) {
      float4 xa = *(const float4*)(xl + p * 32 + c0);
      float4 xb = *(const float4*)(xl + p * 32 + c0 + 4);
      float4 cv = *(const float4*)(cosl + p * DFT_PADS + slot * 4);
      float4 sv = *(const float4*)(sinl + p * DFT_PADS + slot * 4);
      float xs[8] = {xa.x, xa.y, xa.z, xa.w, xb.x, xb.y, xb.z, xb.w};
      float cs[4] = {cv.x, cv.y, cv.z, cv.w};
      float sn[4] = {sv.x, sv.y, sv.z, sv.w};
#pragma unroll
      for (int a = 0; a < 4; ++a)
#pragma unroll
        for (int q = 0; q < 8; ++q) {
          accr[a][q] = fmaf(cs[a], xs[q], accr[a][q]);
          acci[a][q] = fmaf(-sn[a], xs[q], acci[a][q]);
        }
    }
  }
  float wq = ws[OFF_WQ + t];
#pragma unroll
  for (int a = 0; a < 4; ++a) {
    size_t base = ((size_t)(m0 + a) * 256 + t) * 32 + c0;
    *(float4*)(ws + OFF_FRE + base) =
        make_float4(wq * accr[a][0], wq * accr[a][1], wq * accr[a][2], wq * accr[a][3]);
    *(float4*)(ws + OFF_FRE + base + 4) =
        make_float4(wq * accr[a][4], wq * accr[a][5], wq * accr[a][6], wq * accr[a][7]);
    *(float4*)(ws + OFF_FIM + base) =
        make_float4(wq * acci[a][0], wq * acci[a][1], wq * acci[a][2], wq * acci[a][3]);
    *(float4*)(ws + OFF_FIM + base + 4) =
        make_float4(wq * acci[a][4], wq * acci[a][5], wq * acci[a][6], wq * acci[a][7]);
  }
}

// ---------------- forward Legendre contraction: flm[m][l][c] ----------------
__global__ __launch_bounds__(64) void k_legfwd(float* ws) { // grid (8 ltile, 256 m) x 64
  int lt = blockIdx.x, m = blockIdx.y;
  int l0 = lt * 32;
  int tid = threadIdx.x;
  int slot = tid >> 3, cg = tid & 7;   // slot 0..7 (l), cg 0..7 (c: 4 each)
  int c0 = cg * 4;
  float* SFRE = ws + OFF_SFRE;
  float* SFIM = ws + OFF_SFIM;
  if (l0 + 31 < m) { // whole tile is l<m -> zeros
#pragma unroll
    for (int k = 0; k < 4; ++k) {
      int l = l0 + slot + 8 * k;
      size_t base = ((size_t)m * 256 + l) * 32 + c0;
      *(float4*)(SFRE + base) = make_float4(0.f, 0.f, 0.f, 0.f);
      *(float4*)(SFIM + base) = make_float4(0.f, 0.f, 0.f, 0.f);
    }
    return;
  }
  __shared__ float Pl[32 * 65];
  __shared__ __align__(16) float Fre[64 * 32];
  __shared__ __align__(16) float Fim[64 * 32];
  float ar[4][4], ai[4][4];
#pragma unroll
  for (int k = 0; k < 4; ++k)
#pragma unroll
    for (int q = 0; q < 4; ++q) { ar[k][q] = 0.f; ai[k][q] = 0.f; }
  const float* Pg = ws + OFF_P + (size_t)m * 65536;
  const float* FREg = ws + OFF_FRE + (size_t)m * 8192;
  const float* FIMg = ws + OFF_FIM + (size_t)m * 8192;
  for (int ch = 0; ch < 4; ++ch) {
    int t0 = ch * 64;
    __syncthreads();
#pragma unroll
    for (int r = 0; r < 8; ++r) {  // P tile 32l x 64t
      int idx4 = tid + 64 * r;     // 0..511
      int ll = idx4 >> 4, t4 = (idx4 & 15) * 4;
      float4 pv = ld4(Pg + (size_t)(l0 + ll) * 256 + t0 + t4);
      float* d = Pl + ll * 65 + t4;
      d[0] = pv.x; d[1] = pv.y; d[2] = pv.z; d[3] = pv.w;
    }
#pragma unroll
    for (int r = 0; r < 8; ++r) {  // F tiles 64t x 32c
      int idx4 = tid + 64 * r;
      int tt = idx4 >> 3, c4 = (idx4 & 7) * 4;
      *(float4*)(Fre + tt * 32 + c4) = ld4(FREg + (size_t)(t0 + tt) * 32 + c4);
      *(float4*)(Fim + tt * 32 + c4) = ld4(FIMg + (size_t)(t0 + tt) * 32 + c4);
    }
    __syncthreads();
    for (int tt = 0; tt < 64; ++tt) {
      float4 fr = *(const float4*)(Fre + tt * 32 + c0);
      float4 fi = *(const float4*)(Fim + tt * 32 + c0);
#pragma unroll
      for (int k = 0; k < 4; ++k) {
        float pv = Pl[(slot + 8 * k) * 65 + tt];
        ar[k][0] = fmaf(pv, fr.x, ar[k][0]); ai[k][0] = fmaf(pv, fi.x, ai[k][0]);
        ar[k][1] = fmaf(pv, fr.y, ar[k][1]); ai[k][1] = fmaf(pv, fi.y, ai[k][1]);
        ar[k][2] = fmaf(pv, fr.z, ar[k][2]); ai[k][2] = fmaf(pv, fi.z, ai[k][2]);
        ar[k][3] = fmaf(pv, fr.w, ar[k][3]); ai[k][3] = fmaf(pv, fi.w, ai[k][3]);
      }
    }
  }
#pragma unroll
  for (int k = 0; k < 4; ++k) {
    int l = l0 + slot + 8 * k;
    size_t base = ((size_t)m * 256 + l) * 32 + c0;
    *(float4*)(SFRE + base) = make_float4(ar[k][0], ar[k][1], ar[k][2], ar[k][3]);
    *(float4*)(SFIM + base) = make_float4(ai[k][0], ai[k][1], ai[k][2], ai[k][3]);
  }
}

// ---------------- bilinear (antialias) resize, fused 2-D taps ----------------
__global__ __launch_bounds__(256) void k_resize(float* ws) { // grid 4080 x 256
  int tid = threadIdx.x;
  int p = blockIdx.x * 8 + (tid >> 5);   // pair index j'*128 + l', < 32640
  int c = tid & 31;
  int lp = p & 127, jp = p >> 7;
  const float* WLW = ws + OFF_WLW;
  const int* WLI = (const int*)(ws + OFF_WLI);
  const float* WMW = ws + OFF_WMW;
  const int* WMI = (const int*)(ws + OFF_WMI);
  const float* SFRE = ws + OFF_SFRE;
  const float* SFIM = ws + OFF_SFIM;
  float accr = 0.f, acci = 0.f;
  for (int b = 0; b < 6; ++b) {
    float wm = WMW[jp * 6 + b];
    int jm = WMI[jp * 6 + b];          // 0..510 (m index in full grid)
    bool mneg = (jm < 255);
    int mm = mneg ? (255 - jm) : (jm - 255);
    float fre_f = (mneg && (mm & 1)) ? -1.f : 1.f;
    float fim_f = mneg ? -fre_f : 1.f;
#pragma unroll
    for (int a = 0; a < 4; ++a) {
      float w = wm * WLW[lp * 4 + a];
      int li = WLI[lp * 4 + a];
      size_t base = ((size_t)mm * 256 + li) * 32 + c;
      accr = fmaf(w * fre_f, SFRE[base], accr);
      acci = fmaf(w * fim_f, SFIM[base], acci);
    }
  }
  ws[OFF_RRE + ((size_t)jp * 128 + lp) * 32 + c] = accr;
  ws[OFF_RIM + ((size_t)jp * 128 + lp) * 32 + c] = acci;
}

// ---------------- per-l complex channel mix ----------------
__global__ __launch_bounds__(256) void k_conv(float* ws) { // grid (32 jg, 128 l) x 256
  int jg = blockIdx.x, l = blockIdx.y;
  int tid = threadIdx.x;
  int jl = tid >> 5, o = tid & 31;
  int j = jg * 8 + jl;
  int jc = (j < 255) ? j : 254;
  __shared__ __align__(16) float wr[32 * 36];
  __shared__ __align__(16) float wi[32 * 36];
  __shared__ __align__(16) float fr[8 * 32];
  __shared__ __align__(16) float fi[8 * 32];
  {
    int oo = tid >> 3, i4 = (tid & 7) * 4;
    *(float4*)(wr + oo * 36 + i4) = ld4(ws + OFF_WPR + ((size_t)l * 32 + oo) * 32 + i4);
    *(float4*)(wi + oo * 36 + i4) = ld4(ws + OFF_WPI + ((size_t)l * 32 + oo) * 32 + i4);
  }
  size_t fbase = ((size_t)jc * 128 + l) * 32;
  fr[jl * 32 + o] = ws[OFF_RRE + fbase + o];
  fi[jl * 32 + o] = ws[OFF_RIM + fbase + o];
  __syncthreads();
  float accr = 0.f, acci = 0.f;
#pragma unroll
  for (int i0 = 0; i0 < 32; i0 += 4) {
    float4 f_r = *(const float4*)(fr + jl * 32 + i0);
    float4 f_i = *(const float4*)(fi + jl * 32 + i0);
    float4 w_r = *(const float4*)(wr + o * 36 + i0);
    float4 w_i = *(const float4*)(wi + o * 36 + i0);
    accr += f_r.x * w_r.x - f_i.x * w_i.x;  acci += f_r.x * w_i.x + f_i.x * w_r.x;
    accr += f_r.y * w_r.y - f_i.y * w_i.y;  acci += f_r.y * w_i.y + f_i.y * w_r.y;
    accr += f_r.z * w_r.z - f_i.z * w_i.z;  acci += f_r.z * w_i.z + f_i.z * w_r.z;
    accr += f_r.w * w_r.w - f_i.w * w_i.w;  acci += f_r.w * w_i.w + f_i.w * w_r.w;
  }
  if (j < 255) {
    // fold (-1)^|m| of Pfull for negative m (inverse transform) into the store
    float s = (j < 127 && ((127 - j) & 1)) ? -1.f : 1.f;
    ws[OFF_CRE + ((size_t)j * 128 + l) * 32 + o] = s * accr;
    ws[OFF_CIM + ((size_t)j * 128 + l) * 32 + o] = s * acci;
  }
}

// ---------------- inverse Legendre: G[t][j][c] ----------------
__global__ __launch_bounds__(64) void k_leginv(float* ws) { // grid (8 ttile, 255 j) x 64
  int tt = blockIdx.x, j = blockIdx.y;
  int t0 = tt * 32;
  int tid = threadIdx.x;
  int slot = tid >> 3, cg = tid & 7;
  int c0 = cg * 4;
  int m = j - 127;
  int mm = (m < 0) ? -m : m;
  __shared__ float Pl[64 * 33];
  __shared__ __align__(16) float Cre[64 * 32];
  __shared__ __align__(16) float Cim[64 * 32];
  float ar[4][4], ai[4][4];
#pragma unroll
  for (int k = 0; k < 4; ++k)
#pragma unroll
    for (int q = 0; q < 4; ++q) { ar[k][q] = 0.f; ai[k][q] = 0.f; }
  const float* Pg = ws + OFF_P + (size_t)mm * 65536;
  const float* CREg = ws + OFF_CRE + (size_t)j * 4096;
  const float* CIMg = ws + OFF_CIM + (size_t)j * 4096;
  for (int ch = 0; ch < 2; ++ch) {
    int l0 = ch * 64;
    __syncthreads();
#pragma unroll
    for (int r = 0; r < 8; ++r) {  // P tile 64l x 32t
      int idx4 = tid + 64 * r;     // 0..511
      int ll = idx4 >> 3, t4 = (idx4 & 7) * 4;
      float4 pv = ld4(Pg + (size_t)(l0 + ll) * 256 + t0 + t4);
      float* d = Pl + ll * 33 + t4;
      d[0] = pv.x; d[1] = pv.y; d[2] = pv.z; d[3] = pv.w;
    }
#pragma unroll
    for (int r = 0; r < 8; ++r) {  // C tiles 64l x 32c
      int idx4 = tid + 64 * r;
      int ll = idx4 >> 3, c4 = (idx4 & 7) * 4;
      *(float4*)(Cre + ll * 32 + c4) = ld4(CREg + (size_t)(l0 + ll) * 32 + c4);
      *(float4*)(Cim + ll * 32 + c4) = ld4(CIMg + (size_t)(l0 + ll) * 32 + c4);
    }
    __syncthreads();
    for (int ll = 0; ll < 64; ++ll) {
      float4 cr = *(const float4*)(Cre + ll * 32 + c0);
      float4 ci = *(const float4*)(Cim + ll * 32 + c0);
#pragma unroll
      for (int k = 0; k < 4; ++k) {
        float pv = Pl[ll * 33 + slot + 8 * k];
        ar[k][0] = fmaf(pv, cr.x, ar[k][0]); ai[k][0] = fmaf(pv, ci.x, ai[k][0]);
        ar[k][1] = fmaf(pv, cr.y, ar[k][1]); ai[k][1] = fmaf(pv, ci.y, ai[k][1]);
        ar[k][2] = fmaf(pv, cr.z, ar[k][2]); ai[k][2] = fmaf(pv, ci.z, ai[k][2]);
        ar[k][3] = fmaf(pv, cr.w, ar[k][3]); ai[k][3] = fmaf(pv, ci.w, ai[k][3]);
      }
    }
  }
#pragma unroll
  for (int k = 0; k < 4; ++k) {
    int tloc = t0 + slot + 8 * k;
    size_t base = ((size_t)tloc * 255 + j) * 32 + c0;
    *(float4*)(ws + OFF_GRE + base) = make_float4(ar[k][0], ar[k][1], ar[k][2], ar[k][3]);
    *(float4*)(ws + OFF_GIM + base) = make_float4(ai[k][0], ai[k][1], ai[k][2], ai[k][3]);
  }
}

// ---------------- inverse DFT over m -> real output ----------------
__global__ __launch_bounds__(64) void k_idft(const float* ws, float* out) { // grid (4 pt, 256 t) x 64
  int pt = blockIdx.x, t = blockIdx.y;
  int tid = threadIdx.x;
  int slot = tid >> 2, cg = tid & 3;   // slot 0..15 (8 consecutive phi), cg 0..3 (8 c)
  int c0 = cg * 8;
  int phiB = pt * 128 + slot * 8;
  __shared__ __align__(16) float cl[16 * 132];
  __shared__ __align__(16) float sl[16 * 132];
  __shared__ __align__(16) float gre[16 * 32];
  __shared__ __align__(16) float gim[16 * 32];
  float acc[8][8];
#pragma unroll
  for (int r = 0; r < 8; ++r)
#pragma unroll
    for (int q = 0; q < 8; ++q) acc[r][q] = 0.f;
  const float* COSIg = ws + OFF_COSI;
  const float* SINIg = ws + OFF_SINI;
  const float* GREg = ws + OFF_GRE + (size_t)t * 8160;
  const float* GIMg = ws + OFF_GIM + (size_t)t * 8160;
  for (int ch = 0; ch < 16; ++ch) {
    int j0 = ch * 16;
    __syncthreads();
#pragma unroll
    for (int r = 0; r < 8; ++r) {   // trig tiles 16j x 128phi
      int idx4 = tid + 64 * r;      // 0..511
      int jl = idx4 >> 5, p4 = (idx4 & 31) * 4;
      int j = j0 + jl;
      float4 cv = make_float4(0.f, 0.f, 0.f, 0.f), sv = make_float4(0.f, 0.f, 0.f, 0.f);
      if (j < 255) {
        cv = ld4(COSIg + (size_t)j * 512 + pt * 128 + p4);
        sv = ld4(SINIg + (size_t)j * 512 + pt * 128 + p4);
      }
      *(float4*)(cl + jl * 132 + p4) = cv;
      *(float4*)(sl + jl * 132 + p4) = sv;
    }
#pragma unroll
    for (int r = 0; r < 2; ++r) {   // G tiles 16j x 32c
      int idx4 = tid + 64 * r;      // 0..127
      int jl = idx4 >> 3, c4 = (idx4 & 7) * 4;
      int j = j0 + jl;
      float4 gr = make_float4(0.f, 0.f, 0.f, 0.f), gi = make_float4(0.f, 0.f, 0.f, 0.f);
      if (j < 255) {
        gr = ld4(GREg + (size_t)j * 32 + c4);
        gi = ld4(GIMg + (size_t)j * 32 + c4);
      }
      *(float4*)(gre + jl * 32 + c4) = gr;
      *(float4*)(gim + jl * 32 + c4) = gi;
    }
    __syncthreads();
    for (int jl = 0; jl < 16; ++jl) {
      float4 g0 = *(const float4*)(gre + jl * 32 + c0);
      float4 g1 = *(const float4*)(gre + jl * 32 + c0 + 4);
      float4 h0 = *(const float4*)(gim + jl * 32 + c0);
      float4 h1 = *(const float4*)(gim + jl * 32 + c0 + 4);
      float4 cA = *(const float4*)(cl + jl * 132 + slot * 8);
      float4 cB = *(const float4*)(cl + jl * 132 + slot * 8 + 4);
      float4 sA = *(const float4*)(sl + jl * 132 + slot * 8);
      float4 sB = *(const float4*)(sl + jl * 132 + slot * 8 + 4);
      float gs[8] = {g0.x, g0.y, g0.z, g0.w, g1.x, g1.y, g1.z, g1.w};
      float hs[8] = {h0.x, h0.y, h0.z, h0.w, h1.x, h1.y, h1.z, h1.w};
      float cs[8] = {cA.x, cA.y, cA.z, cA.w, cB.x, cB.y, cB.z, cB.w};
      float sn[8] = {sA.x, sA.y, sA.z, sA.w, sB.x, sB.y, sB.z, sB.w};
#pragma unroll
      for (int r = 0; r < 8; ++r)
#pragma unroll
        for (int q = 0; q < 8; ++q) {
          acc[r][q] = fmaf(cs[r], gs[q], acc[r][q]);
          acc[r][q] = fmaf(-sn[r], hs[q], acc[r][q]);
        }
    }
  }
#pragma unroll
  for (int r = 0; r < 8; ++r) {
    int phi = phiB + r;
    if (phi < 511) {
      size_t base = ((size_t)t * 511 + phi) * 32 + c0;
      *(float4*)(out + base) = make_float4(acc[r][0], acc[r][1], acc[r][2], acc[r][3]);
      *(float4*)(out + base + 4) = make_float4(acc[r][4], acc[r][5], acc[r][6], acc[r][7]);
    }
  }
}

// ---------------- launch ----------------
extern "C" void kernel_launch(void* const* d_in, const int* in_sizes, int n_in,
                              void* d_out, int out_size, void* d_ws, size_t ws_size,
                              hipStream_t stream) {
  const float* x = (const float*)d_in[0];
  const float* t_emb = (const float*)d_in[1];
  const float* w_real = (const float*)d_in[2];
  const float* w_imag = (const float*)d_in[3];
  const float* w_tr = (const float*)d_in[4];
  const float* b_tr = (const float*)d_in[5];
  const float* w_ti = (const float*)d_in[6];
  const float* b_ti = (const float*)d_in[7];
  float* ws = (float*)d_ws;
  float* out = (float*)d_out;
  (void)in_sizes; (void)n_in; (void)out_size; (void)ws_size; // needs ~104 MB workspace

  hipLaunchKernelGGL(k_setup_small, dim3(1), dim3(256), 0, stream,
                     t_emb, w_tr, b_tr, w_ti, b_ti, ws);
  hipLaunchKernelGGL(k_trig_fwd, dim3(511), dim3(256), 0, stream, ws);
  hipLaunchKernelGGL(k_trig_inv, dim3(510), dim3(256), 0, stream, ws);
  hipLaunchKernelGGL(k_wprep, dim3(512), dim3(256), 0, stream, w_real, w_imag, ws);
  hipLaunchKernelGGL(k_legendre, dim3(256), dim3(256), 0, stream, ws);
  hipLaunchKernelGGL(k_dft, dim3(512), dim3(128), 0, stream, x, ws);
  hipLaunchKernelGGL(k_legfwd, dim3(8, 256), dim3(64), 0, stream, ws);
  hipLaunchKernelGGL(k_resize, dim3(4080), dim3(256), 0, stream, ws);
  hipLaunchKernelGGL(k_conv, dim3(32, 128), dim3(256), 0, stream, ws);
  hipLaunchKernelGGL(k_leginv, dim3(8, 255), dim3(64), 0, stream, ws);
  hipLaunchKernelGGL(k_idft, dim3(4, 256), dim3(64), 0, stream, ws, out);
}

// Round 2
// 404.200 us; speedup vs baseline: 1.1296x; 1.1296x over previous
//
#include <hip/hip_runtime.h>
#include <math.h>

#define PI_D 3.14159265358979323846

// ---------------- workspace layout (float offsets) ----------------
// total = 25955328 floats = 103.9 MB
constexpr size_t OFF_P    = 0;                   // P[m][l][t]  256*256*256 (m>=0; zeros for l<m)
constexpr size_t OFF_FRE  = 16777216;            // F'[m][t][c] 256*256*32
constexpr size_t OFF_FIM  = 18874368;
constexpr size_t OFF_SFRE = 20971520;            // flm[m][l][c] 256*256*32 (also dft partial ps=1)
constexpr size_t OFF_SFIM = 23068672;
constexpr size_t OFF_COS  = 25165824;            // fwd trig [phi][m] 511*256
constexpr size_t OFF_SIN  = 25296640;
constexpr size_t OFF_COSI = 25427456;            // inv trig [j][phi(512 pad)] 255*512
constexpr size_t OFF_SINI = 25558016;
constexpr size_t OFF_WPR  = 25688576;            // premult conv w [l][o][i] 128*32*32
constexpr size_t OFF_WPI  = 25819648;
constexpr size_t OFF_WQ   = 25950720;            // 256 quadrature weights
constexpr size_t OFF_TC   = 25950976;            // 256 (t_cplx re|im)
constexpr size_t OFF_WLW  = 25951232;            // 128*4 l-resize weights
constexpr size_t OFF_WLI  = 25951744;            // 128*4 l-resize indices (int)
constexpr size_t OFF_WMW  = 25952256;            // 255*6 m-resize weights (pad 1536)
constexpr size_t OFF_WMI  = 25953792;            // 255*6 m-resize indices (int)
// overlays (lifetimes disjoint):
constexpr size_t OFF_RRE  = OFF_FRE;             // resized flm [j'][l'][c] 255*128*32
constexpr size_t OFF_RIM  = OFF_FRE + 1044480;
constexpr size_t OFF_CRE  = OFF_FIM;             // conv out    [j][l][o]
constexpr size_t OFF_CIM  = OFF_FIM + 1044480;
constexpr size_t OFF_GRE  = OFF_SFRE;            // G [t][j][c] 256*255*32
constexpr size_t OFF_GIM  = OFF_SFRE + 2088960;
// idft partials: ps0 -> OFF_FRE (4186112 floats fits FRE+FIM = 4194304),
//                ps1 -> OFF_P   (P is dead after k_leginv)

__device__ __forceinline__ float4 ld4(const float* p) { return *(const float4*)p; }

// ---------------- setup: quadrature, t_cplx, resize taps ----------------
__global__ void k_setup_small(const float* t_emb, const float* w_tr, const float* b_tr,
                              const float* w_ti, const float* b_ti, float* ws) {
  int tid = threadIdx.x;
  if (tid < 256) {
    double theta = PI_D * (2.0 * tid + 1.0) / 511.0;
    double dang = 2.0 * PI_D / 511.0;
    ws[OFF_WQ + tid] = (float)(sin(theta) * dang * dang);
  }
  if (tid < 128) {
    float sr = b_tr[tid], si = b_ti[tid];
    for (int T = 0; T < 256; ++T) {
      float e = t_emb[T];
      sr += e * w_tr[T * 128 + tid];
      si += e * w_ti[T * 128 + tid];
    }
    ws[OFF_TC + tid] = sr;
    ws[OFF_TC + 128 + tid] = si;
    double sf = 2.0 * tid + 0.5;
    double wv[4]; int iv[4]; double wsum = 0.0;
    for (int a = 0; a < 4; ++a) {
      int t = 2 * tid - 1 + a;
      double r = 1.0 - fabs(sf - (double)t) * 0.5;
      bool valid = (t >= 0 && t < 256 && r > 0.0);
      wv[a] = valid ? r : 0.0; iv[a] = valid ? t : 0;
      wsum += wv[a];
    }
    for (int a = 0; a < 4; ++a) {
      ws[OFF_WLW + tid * 4 + a] = (float)(wv[a] / wsum);
      ((int*)(ws + OFF_WLI))[tid * 4 + a] = iv[a];
    }
  }
  if (tid < 255) {
    double inv = 511.0 / 255.0;
    double sf = (tid + 0.5) * inv - 0.5;
    int t0 = (int)floor(sf) - 2;
    double wv[6]; int iv[6]; double wsum = 0.0;
    for (int b = 0; b < 6; ++b) {
      int t = t0 + b;
      double r = 1.0 - fabs(sf - (double)t) * (255.0 / 511.0);
      bool valid = (t >= 0 && t < 511 && r > 0.0);
      wv[b] = valid ? r : 0.0; iv[b] = valid ? t : 0;
      wsum += wv[b];
    }
    for (int b = 0; b < 6; ++b) {
      ws[OFF_WMW + tid * 6 + b] = (float)(wv[b] / wsum);
      ((int*)(ws + OFF_WMI))[tid * 6 + b] = iv[b];
    }
  }
}

// ---------------- trig tables ----------------
__global__ void k_trig_fwd(float* ws) {   // grid 511 x 256
  int gid = blockIdx.x * 256 + threadIdx.x;
  int phi = gid >> 8, m = gid & 255;
  int k = (m * phi) % 511;
  double ang = (2.0 * PI_D / 511.0) * (double)k;
  ws[OFF_COS + gid] = (float)cos(ang);
  ws[OFF_SIN + gid] = (float)sin(ang);
}

__global__ void k_trig_inv(float* ws) {   // grid 510 x 256 -> 255*512
  int gid = blockIdx.x * 256 + threadIdx.x;
  int j = gid >> 9, p = gid & 511;
  float cv = 0.f, sv = 0.f;
  if (p < 511) {
    int m = j - 127;
    int k = ((m * p) % 511 + 511) % 511;
    double ang = (2.0 * PI_D / 511.0) * (double)k;
    cv = (float)cos(ang); sv = (float)sin(ang);
  }
  ws[OFF_COSI + gid] = cv;
  ws[OFF_SINI + gid] = sv;
}

// ---------------- premultiplied conv weights, transposed [l][o][i] ----------------
__global__ void k_wprep(const float* wr_, const float* wi_, float* ws) { // grid 512 x 256
  int gid = blockIdx.x * 256 + threadIdx.x;
  int l = gid >> 10, rem = gid & 1023, o = rem >> 5, i = rem & 31;
  float wr = wr_[(l << 10) + i * 32 + o];
  float wi = wi_[(l << 10) + i * 32 + o];
  float tcr = ws[OFF_TC + l], tci = ws[OFF_TC + 128 + l];
  ws[OFF_WPR + gid] = tcr * wr - tci * wi;
  ws[OFF_WPI + gid] = tcr * wi + tci * wr;
}

// ---------------- Legendre basis (fp64, coefficients staged in LDS) ----------------
__global__ void k_legendre(float* ws) {   // grid 256 (m) x 256 (t)
  int m = blockIdx.x, t = threadIdx.x;
  __shared__ double A[256], B[256], S[256];
  {
    int l = t;
    if (l >= 1) S[l] = -sqrt((2.0 * l + 1.0) / (2.0 * l));
    if (l >= m + 2) {
      double ll = l, mm = m;
      double den = ll * ll - mm * mm;
      A[l] = sqrt((4.0 * ll * ll - 1.0) / den);
      B[l] = sqrt((2.0 * ll + 1.0) * (ll - 1.0 - mm) * (ll - 1.0 + mm) /
                  ((2.0 * ll - 3.0) * den));
    }
  }
  __syncthreads();
  double theta = PI_D * (2.0 * t + 1.0) / 511.0;
  double ct = cos(theta), st = sin(theta);
  float* Pm = ws + OFF_P + (size_t)m * 65536 + t;
  double p0 = sqrt(1.0 / (4.0 * PI_D));
  for (int k = 1; k <= m; ++k) p0 *= S[k] * st;
  for (int l = 0; l < m; ++l) Pm[(size_t)l * 256] = 0.f;
  Pm[(size_t)m * 256] = (float)p0;
  if (m + 1 < 256) {
    double p1 = sqrt(2.0 * m + 3.0) * ct * p0;
    Pm[(size_t)(m + 1) * 256] = (float)p1;
    for (int l = m + 2; l < 256; ++l) {
      double p2 = A[l] * ct * p1 - B[l] * p0;
      Pm[(size_t)l * 256] = (float)p2;
      p0 = p1; p1 = p2;
    }
  }
}

// ---------------- forward DFT over phi: phi-split partials ----------------
// grid (mh 2, ps 2, t 256) x 128; thread: slot=tid>>2 -> m = m_base+slot+32a, cg -> 8c
__global__ __launch_bounds__(128) void k_dft(const float* x, float* ws) {
  int mh = blockIdx.x, ps = blockIdx.y, t = blockIdx.z;
  int tid = threadIdx.x;
  int slot = tid >> 2, cg = tid & 3;
  int c0 = cg * 8;
  int m_base = mh << 7;
  __shared__ __align__(16) float cosl[32 * 132];
  __shared__ __align__(16) float sinl[32 * 132];
  __shared__ __align__(16) float xl[32 * 32];
  float accr[4][8], acci[4][8];
#pragma unroll
  for (int a = 0; a < 4; ++a)
#pragma unroll
    for (int q = 0; q < 8; ++q) { accr[a][q] = 0.f; acci[a][q] = 0.f; }
  const float* COSg = ws + OFF_COS;
  const float* SINg = ws + OFF_SIN;
  int phiB = ps * 256;
  for (int ch = 0; ch < 8; ++ch) {
    int phi0 = phiB + ch * 32;
    __syncthreads();
#pragma unroll
    for (int r = 0; r < 8; ++r) {   // trig tile [32 p][128 m]
      int idx4 = tid + 128 * r;     // 0..1023
      int p = idx4 >> 5, m4 = (idx4 & 31) * 4;
      int phi = phi0 + p;
      float4 cv = make_float4(0.f, 0.f, 0.f, 0.f), sv = make_float4(0.f, 0.f, 0.f, 0.f);
      if (phi < 511) {
        cv = ld4(COSg + (size_t)phi * 256 + m_base + m4);
        sv = ld4(SINg + (size_t)phi * 256 + m_base + m4);
      }
      *(float4*)(cosl + p * 132 + m4) = cv;
      *(float4*)(sinl + p * 132 + m4) = sv;
    }
#pragma unroll
    for (int r = 0; r < 2; ++r) {   // x tile [32 p][32 c]
      int idx4 = tid + 128 * r;     // 0..255
      int p = idx4 >> 3, c4 = (idx4 & 7) * 4;
      int phi = phi0 + p;
      float4 xv = make_float4(0.f, 0.f, 0.f, 0.f);
      if (phi < 511) xv = ld4(x + ((size_t)t * 511 + phi) * 32 + c4);
      *(float4*)(xl + p * 32 + c4) = xv;
    }
    __syncthreads();
    for (int p = 0; p < 32; ++p) {
      float4 xa = *(const float4*)(xl + p * 32 + c0);
      float4 xb = *(const float4*)(xl + p * 32 + c0 + 4);
      float xs[8] = {xa.x, xa.y, xa.z, xa.w, xb.x, xb.y, xb.z, xb.w};
      float cs[4], sn[4];
#pragma unroll
      for (int a = 0; a < 4; ++a) {
        cs[a] = cosl[p * 132 + slot + 32 * a];   // consecutive banks, 4-lane broadcast
        sn[a] = sinl[p * 132 + slot + 32 * a];
      }
#pragma unroll
      for (int a = 0; a < 4; ++a)
#pragma unroll
        for (int q = 0; q < 8; ++q) {
          accr[a][q] = fmaf(cs[a], xs[q], accr[a][q]);
          acci[a][q] = fmaf(-sn[a], xs[q], acci[a][q]);
        }
    }
  }
  float* RE = ws + (ps ? OFF_SFRE : OFF_FRE);
  float* IM = ws + (ps ? OFF_SFIM : OFF_FIM);
#pragma unroll
  for (int a = 0; a < 4; ++a) {
    int m = m_base + slot + 32 * a;
    size_t base = ((size_t)m * 256 + t) * 32 + c0;
    *(float4*)(RE + base) = make_float4(accr[a][0], accr[a][1], accr[a][2], accr[a][3]);
    *(float4*)(RE + base + 4) = make_float4(accr[a][4], accr[a][5], accr[a][6], accr[a][7]);
    *(float4*)(IM + base) = make_float4(acci[a][0], acci[a][1], acci[a][2], acci[a][3]);
    *(float4*)(IM + base + 4) = make_float4(acci[a][4], acci[a][5], acci[a][6], acci[a][7]);
  }
}

// combine dft partials, apply wq: FRE = wq*(FRE+SFRE), FIM = wq*(FIM+SFIM)
__global__ void k_dft_combine(float* ws) {  // grid 2048 x 256, float4 per thread
  int gid = blockIdx.x * 256 + threadIdx.x;   // < 524288
  int t = (gid >> 3) & 255;                   // layout [m][t][c], 8 float4 per (m,t)
  float wq = ws[OFF_WQ + t];
  size_t o = (size_t)gid * 4;
  float4 a = ld4(ws + OFF_FRE + o), b = ld4(ws + OFF_SFRE + o);
  *(float4*)(ws + OFF_FRE + o) =
      make_float4(wq * (a.x + b.x), wq * (a.y + b.y), wq * (a.z + b.z), wq * (a.w + b.w));
  float4 c = ld4(ws + OFF_FIM + o), d = ld4(ws + OFF_SFIM + o);
  *(float4*)(ws + OFF_FIM + o) =
      make_float4(wq * (c.x + d.x), wq * (c.y + d.y), wq * (c.z + d.z), wq * (c.w + d.w));
}

// ---------------- forward Legendre contraction: flm[m][l][c] ----------------
__global__ __launch_bounds__(64) void k_legfwd(float* ws) { // grid (8 ltile, 256 m) x 64
  int lt = blockIdx.x, m = blockIdx.y;
  int l0 = lt * 32;
  int tid = threadIdx.x;
  int slot = tid >> 3, cg = tid & 7;
  int c0 = cg * 4;
  float* SFRE = ws + OFF_SFRE;
  float* SFIM = ws + OFF_SFIM;
  if (l0 + 31 < m) {
#pragma unroll
    for (int k = 0; k < 4; ++k) {
      int l = l0 + slot + 8 * k;
      size_t base = ((size_t)m * 256 + l) * 32 + c0;
      *(float4*)(SFRE + base) = make_float4(0.f, 0.f, 0.f, 0.f);
      *(float4*)(SFIM + base) = make_float4(0.f, 0.f, 0.f, 0.f);
    }
    return;
  }
  __shared__ float Pl[32 * 65];
  __shared__ __align__(16) float Fre[64 * 32];
  __shared__ __align__(16) float Fim[64 * 32];
  float ar[4][4], ai[4][4];
#pragma unroll
  for (int k = 0; k < 4; ++k)
#pragma unroll
    for (int q = 0; q < 4; ++q) { ar[k][q] = 0.f; ai[k][q] = 0.f; }
  const float* Pg = ws + OFF_P + (size_t)m * 65536;
  const float* FREg = ws + OFF_FRE + (size_t)m * 8192;
  const float* FIMg = ws + OFF_FIM + (size_t)m * 8192;
  for (int ch = 0; ch < 4; ++ch) {
    int t0 = ch * 64;
    __syncthreads();
#pragma unroll
    for (int r = 0; r < 8; ++r) {
      int idx4 = tid + 64 * r;
      int ll = idx4 >> 4, t4 = (idx4 & 15) * 4;
      float4 pv = ld4(Pg + (size_t)(l0 + ll) * 256 + t0 + t4);
      float* d = Pl + ll * 65 + t4;
      d[0] = pv.x; d[1] = pv.y; d[2] = pv.z; d[3] = pv.w;
    }
#pragma unroll
    for (int r = 0; r < 8; ++r) {
      int idx4 = tid + 64 * r;
      int tt = idx4 >> 3, c4 = (idx4 & 7) * 4;
      *(float4*)(Fre + tt * 32 + c4) = ld4(FREg + (size_t)(t0 + tt) * 32 + c4);
      *(float4*)(Fim + tt * 32 + c4) = ld4(FIMg + (size_t)(t0 + tt) * 32 + c4);
    }
    __syncthreads();
    for (int tt = 0; tt < 64; ++tt) {
      float4 fr = *(const float4*)(Fre + tt * 32 + c0);
      float4 fi = *(const float4*)(Fim + tt * 32 + c0);
#pragma unroll
      for (int k = 0; k < 4; ++k) {
        float pv = Pl[(slot + 8 * k) * 65 + tt];
        ar[k][0] = fmaf(pv, fr.x, ar[k][0]); ai[k][0] = fmaf(pv, fi.x, ai[k][0]);
        ar[k][1] = fmaf(pv, fr.y, ar[k][1]); ai[k][1] = fmaf(pv, fi.y, ai[k][1]);
        ar[k][2] = fmaf(pv, fr.z, ar[k][2]); ai[k][2] = fmaf(pv, fi.z, ai[k][2]);
        ar[k][3] = fmaf(pv, fr.w, ar[k][3]); ai[k][3] = fmaf(pv, fi.w, ai[k][3]);
      }
    }
  }
#pragma unroll
  for (int k = 0; k < 4; ++k) {
    int l = l0 + slot + 8 * k;
    size_t base = ((size_t)m * 256 + l) * 32 + c0;
    *(float4*)(SFRE + base) = make_float4(ar[k][0], ar[k][1], ar[k][2], ar[k][3]);
    *(float4*)(SFIM + base) = make_float4(ai[k][0], ai[k][1], ai[k][2], ai[k][3]);
  }
}

// ---------------- bilinear (antialias) resize, fused 2-D taps ----------------
__global__ __launch_bounds__(256) void k_resize(float* ws) { // grid 4080 x 256
  int tid = threadIdx.x;
  int p = blockIdx.x * 8 + (tid >> 5);
  int c = tid & 31;
  int lp = p & 127, jp = p >> 7;
  const float* WLW = ws + OFF_WLW;
  const int* WLI = (const int*)(ws + OFF_WLI);
  const float* WMW = ws + OFF_WMW;
  const int* WMI = (const int*)(ws + OFF_WMI);
  const float* SFRE = ws + OFF_SFRE;
  const float* SFIM = ws + OFF_SFIM;
  float accr = 0.f, acci = 0.f;
  for (int b = 0; b < 6; ++b) {
    float wm = WMW[jp * 6 + b];
    int jm = WMI[jp * 6 + b];
    bool mneg = (jm < 255);
    int mm = mneg ? (255 - jm) : (jm - 255);
    float fre_f = (mneg && (mm & 1)) ? -1.f : 1.f;
    float fim_f = mneg ? -fre_f : 1.f;
#pragma unroll
    for (int a = 0; a < 4; ++a) {
      float w = wm * WLW[lp * 4 + a];
      int li = WLI[lp * 4 + a];
      size_t base = ((size_t)mm * 256 + li) * 32 + c;
      accr = fmaf(w * fre_f, SFRE[base], accr);
      acci = fmaf(w * fim_f, SFIM[base], acci);
    }
  }
  ws[OFF_RRE + ((size_t)jp * 128 + lp) * 32 + c] = accr;
  ws[OFF_RIM + ((size_t)jp * 128 + lp) * 32 + c] = acci;
}

// ---------------- per-l complex channel mix ----------------
__global__ __launch_bounds__(256) void k_conv(float* ws) { // grid (32 jg, 128 l) x 256
  int jg = blockIdx.x, l = blockIdx.y;
  int tid = threadIdx.x;
  int jl = tid >> 5, o = tid & 31;
  int j = jg * 8 + jl;
  int jc = (j < 255) ? j : 254;
  __shared__ __align__(16) float wr[32 * 36];
  __shared__ __align__(16) float wi[32 * 36];
  __shared__ __align__(16) float fr[8 * 32];
  __shared__ __align__(16) float fi[8 * 32];
  {
    int oo = tid >> 3, i4 = (tid & 7) * 4;
    *(float4*)(wr + oo * 36 + i4) = ld4(ws + OFF_WPR + ((size_t)l * 32 + oo) * 32 + i4);
    *(float4*)(wi + oo * 36 + i4) = ld4(ws + OFF_WPI + ((size_t)l * 32 + oo) * 32 + i4);
  }
  size_t fbase = ((size_t)jc * 128 + l) * 32;
  fr[jl * 32 + o] = ws[OFF_RRE + fbase + o];
  fi[jl * 32 + o] = ws[OFF_RIM + fbase + o];
  __syncthreads();
  float accr = 0.f, acci = 0.f;
#pragma unroll
  for (int i0 = 0; i0 < 32; i0 += 4) {
    float4 f_r = *(const float4*)(fr + jl * 32 + i0);
    float4 f_i = *(const float4*)(fi + jl * 32 + i0);
    float4 w_r = *(const float4*)(wr + o * 36 + i0);
    float4 w_i = *(const float4*)(wi + o * 36 + i0);
    accr += f_r.x * w_r.x - f_i.x * w_i.x;  acci += f_r.x * w_i.x + f_i.x * w_r.x;
    accr += f_r.y * w_r.y - f_i.y * w_i.y;  acci += f_r.y * w_i.y + f_i.y * w_r.y;
    accr += f_r.z * w_r.z - f_i.z * w_i.z;  acci += f_r.z * w_i.z + f_i.z * w_r.z;
    accr += f_r.w * w_r.w - f_i.w * w_i.w;  acci += f_r.w * w_i.w + f_i.w * w_r.w;
  }
  if (j < 255) {
    float s = (j < 127 && ((127 - j) & 1)) ? -1.f : 1.f;
    ws[OFF_CRE + ((size_t)j * 128 + l) * 32 + o] = s * accr;
    ws[OFF_CIM + ((size_t)j * 128 + l) * 32 + o] = s * acci;
  }
}

// ---------------- inverse Legendre: G[t][j][c] ----------------
__global__ __launch_bounds__(64) void k_leginv(float* ws) { // grid (8 ttile, 255 j) x 64
  int tt = blockIdx.x, j = blockIdx.y;
  int t0 = tt * 32;
  int tid = threadIdx.x;
  int slot = tid >> 3, cg = tid & 7;
  int c0 = cg * 4;
  int m = j - 127;
  int mm = (m < 0) ? -m : m;
  __shared__ float Pl[64 * 33];
  __shared__ __align__(16) float Cre[64 * 32];
  __shared__ __align__(16) float Cim[64 * 32];
  float ar[4][4], ai[4][4];
#pragma unroll
  for (int k = 0; k < 4; ++k)
#pragma unroll
    for (int q = 0; q < 4; ++q) { ar[k][q] = 0.f; ai[k][q] = 0.f; }
  const float* Pg = ws + OFF_P + (size_t)mm * 65536;
  const float* CREg = ws + OFF_CRE + (size_t)j * 4096;
  const float* CIMg = ws + OFF_CIM + (size_t)j * 4096;
  for (int ch = 0; ch < 2; ++ch) {
    int l0 = ch * 64;
    __syncthreads();
#pragma unroll
    for (int r = 0; r < 8; ++r) {
      int idx4 = tid + 64 * r;
      int ll = idx4 >> 3, t4 = (idx4 & 7) * 4;
      float4 pv = ld4(Pg + (size_t)(l0 + ll) * 256 + t0 + t4);
      float* d = Pl + ll * 33 + t4;
      d[0] = pv.x; d[1] = pv.y; d[2] = pv.z; d[3] = pv.w;
    }
#pragma unroll
    for (int r = 0; r < 8; ++r) {
      int idx4 = tid + 64 * r;
      int ll = idx4 >> 3, c4 = (idx4 & 7) * 4;
      *(float4*)(Cre + ll * 32 + c4) = ld4(CREg + (size_t)(l0 + ll) * 32 + c4);
      *(float4*)(Cim + ll * 32 + c4) = ld4(CIMg + (size_t)(l0 + ll) * 32 + c4);
    }
    __syncthreads();
    for (int ll = 0; ll < 64; ++ll) {
      float4 cr = *(const float4*)(Cre + ll * 32 + c0);
      float4 ci = *(const float4*)(Cim + ll * 32 + c0);
#pragma unroll
      for (int k = 0; k < 4; ++k) {
        float pv = Pl[ll * 33 + slot + 8 * k];
        ar[k][0] = fmaf(pv, cr.x, ar[k][0]); ai[k][0] = fmaf(pv, ci.x, ai[k][0]);
        ar[k][1] = fmaf(pv, cr.y, ar[k][1]); ai[k][1] = fmaf(pv, ci.y, ai[k][1]);
        ar[k][2] = fmaf(pv, cr.z, ar[k][2]); ai[k][2] = fmaf(pv, ci.z, ai[k][2]);
        ar[k][3] = fmaf(pv, cr.w, ar[k][3]); ai[k][3] = fmaf(pv, ci.w, ai[k][3]);
      }
    }
  }
#pragma unroll
  for (int k = 0; k < 4; ++k) {
    int tloc = t0 + slot + 8 * k;
    size_t base = ((size_t)tloc * 255 + j) * 32 + c0;
    *(float4*)(ws + OFF_GRE + base) = make_float4(ar[k][0], ar[k][1], ar[k][2], ar[k][3]);
    *(float4*)(ws + OFF_GIM + base) = make_float4(ai[k][0], ai[k][1], ai[k][2], ai[k][3]);
  }
}

// ---------------- inverse DFT over m (j-split partials) ----------------
// grid (js 2, t 256) x 256; thread: slot=tid>>2 -> phi = slot+64r, cg -> 8c
__global__ __launch_bounds__(256) void k_idft(float* ws) {
  int js = blockIdx.x, t = blockIdx.y;
  int tid = threadIdx.x;
  int slot = tid >> 2, cg = tid & 3;
  int c0 = cg * 8;
  __shared__ float cl[8 * 520];
  __shared__ float sl[8 * 520];
  __shared__ __align__(16) float gre[8 * 32];
  __shared__ __align__(16) float gim[8 * 32];
  float acc[8][8];
#pragma unroll
  for (int r = 0; r < 8; ++r)
#pragma unroll
    for (int q = 0; q < 8; ++q) acc[r][q] = 0.f;
  const float* COSIg = ws + OFF_COSI;
  const float* SINIg = ws + OFF_SINI;
  const float* GREg = ws + OFF_GRE + (size_t)t * 8160;
  const float* GIMg = ws + OFF_GIM + (size_t)t * 8160;
  for (int jc = 0; jc < 16; ++jc) {
    int j0 = js * 128 + jc * 8;
    __syncthreads();
#pragma unroll
    for (int r = 0; r < 4; ++r) {   // trig tile [8 j][512 phi]
      int idx4 = tid + 256 * r;     // 0..1023
      int jl = idx4 >> 7, p4 = (idx4 & 127) * 4;
      int j = j0 + jl;
      float4 cv = make_float4(0.f, 0.f, 0.f, 0.f), sv = make_float4(0.f, 0.f, 0.f, 0.f);
      if (j < 255) {
        cv = ld4(COSIg + (size_t)j * 512 + p4);
        sv = ld4(SINIg + (size_t)j * 512 + p4);
      }
      *(float4*)(cl + jl * 520 + p4) = cv;
      *(float4*)(sl + jl * 520 + p4) = sv;
    }
    if (tid < 128) {                // g/h tiles [8 j][32 c]
      int buf = tid >> 6, jl = (tid & 63) >> 3, c4 = (tid & 7) * 4;
      int j = j0 + jl;
      float4 gv = make_float4(0.f, 0.f, 0.f, 0.f);
      if (j < 255) gv = ld4((buf ? GIMg : GREg) + (size_t)j * 32 + c4);
      *(float4*)((buf ? gim : gre) + jl * 32 + c4) = gv;
    }
    __syncthreads();
    for (int jl = 0; jl < 8; ++jl) {
      float4 g0 = *(const float4*)(gre + jl * 32 + c0);
      float4 g1 = *(const float4*)(gre + jl * 32 + c0 + 4);
      float4 h0 = *(const float4*)(gim + jl * 32 + c0);
      float4 h1 = *(const float4*)(gim + jl * 32 + c0 + 4);
      float gs[8] = {g0.x, g0.y, g0.z, g0.w, g1.x, g1.y, g1.z, g1.w};
      float hs[8] = {h0.x, h0.y, h0.z, h0.w, h1.x, h1.y, h1.z, h1.w};
      float cs[8], sn[8];
#pragma unroll
      for (int r = 0; r < 8; ++r) {
        cs[r] = cl[jl * 520 + slot + 64 * r];   // consecutive banks, broadcast
        sn[r] = sl[jl * 520 + slot + 64 * r];
      }
#pragma unroll
      for (int r = 0; r < 8; ++r)
#pragma unroll
        for (int q = 0; q < 8; ++q) {
          acc[r][q] = fmaf(cs[r], gs[q], acc[r][q]);
          acc[r][q] = fmaf(-sn[r], hs[q], acc[r][q]);
        }
    }
  }
  float* PB = ws + (js ? OFF_P : OFF_FRE);
#pragma unroll
  for (int r = 0; r < 8; ++r) {
    int phi = slot + 64 * r;
    if (phi < 511) {
      size_t base = ((size_t)t * 511 + phi) * 32 + c0;
      *(float4*)(PB + base) = make_float4(acc[r][0], acc[r][1], acc[r][2], acc[r][3]);
      *(float4*)(PB + base + 4) = make_float4(acc[r][4], acc[r][5], acc[r][6], acc[r][7]);
    }
  }
}

__global__ void k_idft_combine(const float* ws, float* out) { // grid 4088 x 256
  int gid = blockIdx.x * 256 + threadIdx.x;   // < 1046528
  size_t o = (size_t)gid * 4;
  float4 a = ld4(ws + OFF_FRE + o);
  float4 b = ld4(ws + OFF_P + o);
  *(float4*)(out + o) = make_float4(a.x + b.x, a.y + b.y, a.z + b.z, a.w + b.w);
}

// ---------------- launch ----------------
extern "C" void kernel_launch(void* const* d_in, const int* in_sizes, int n_in,
                              void* d_out, int out_size, void* d_ws, size_t ws_size,
                              hipStream_t stream) {
  const float* x = (const float*)d_in[0];
  const float* t_emb = (const float*)d_in[1];
  const float* w_real = (const float*)d_in[2];
  const float* w_imag = (const float*)d_in[3];
  const float* w_tr = (const float*)d_in[4];
  const float* b_tr = (const float*)d_in[5];
  const float* w_ti = (const float*)d_in[6];
  const float* b_ti = (const float*)d_in[7];
  float* ws = (float*)d_ws;
  float* out = (float*)d_out;
  (void)in_sizes; (void)n_in; (void)out_size; (void)ws_size;

  hipLaunchKernelGGL(k_setup_small, dim3(1), dim3(256), 0, stream,
                     t_emb, w_tr, b_tr, w_ti, b_ti, ws);
  hipLaunchKernelGGL(k_trig_fwd, dim3(511), dim3(256), 0, stream, ws);
  hipLaunchKernelGGL(k_trig_inv, dim3(510), dim3(256), 0, stream, ws);
  hipLaunchKernelGGL(k_wprep, dim3(512), dim3(256), 0, stream, w_real, w_imag, ws);
  hipLaunchKernelGGL(k_legendre, dim3(256), dim3(256), 0, stream, ws);
  hipLaunchKernelGGL(k_dft, dim3(2, 2, 256), dim3(128), 0, stream, x, ws);
  hipLaunchKernelGGL(k_dft_combine, dim3(2048), dim3(256), 0, stream, ws);
  hipLaunchKernelGGL(k_legfwd, dim3(8, 256), dim3(64), 0, stream, ws);
  hipLaunchKernelGGL(k_resize, dim3(4080), dim3(256), 0, stream, ws);
  hipLaunchKernelGGL(k_conv, dim3(32, 128), dim3(256), 0, stream, ws);
  hipLaunchKernelGGL(k_leginv, dim3(8, 255), dim3(64), 0, stream, ws);
  hipLaunchKernelGGL(k_idft, dim3(2, 256), dim3(256), 0, stream, ws);
  hipLaunchKernelGGL(k_idft_combine, dim3(4088), dim3(256), 0, stream, ws, out);
}

// Round 3
// 254.073 us; speedup vs baseline: 1.7971x; 1.5909x over previous
//
#include <hip/hip_runtime.h>
#include <math.h>

#define PI_D 3.14159265358979323846

typedef short v8s __attribute__((ext_vector_type(8)));
typedef float v4f __attribute__((ext_vector_type(4)));

// ---------------- workspace layout (float offsets) ----------------
// total = 25955328 floats = 103.9 MB (same footprint as R1/R2)
constexpr size_t OFF_P    = 0;                   // P[m][l][t]  256*256*256 fp32
constexpr size_t OFF_FRE  = 16777216;            // F'[m][t][c] 256*256*32 fp32 (wq folded)
constexpr size_t OFF_FIM  = 18874368;
constexpr size_t OFF_SFRE = 20971520;            // flm[m][l][c] 256*256*32 fp32
constexpr size_t OFF_SFIM = 23068672;
constexpr size_t OFF_AF   = 25165824;            // fwd A frags bf16 [mt32][ks16][lane64][8] = 512 KB
constexpr size_t OFF_AI   = 25296896;            // inv A frags bf16, 512 KB
constexpr size_t OFF_WPR  = 25688576;            // premult conv w [l][o][i] 128*32*32
constexpr size_t OFF_WPI  = 25819648;
constexpr size_t OFF_WQ   = 25950720;            // 256 quadrature weights
constexpr size_t OFF_TC   = 25950976;            // 256 (t_cplx re|im)
constexpr size_t OFF_WLW  = 25951232;            // 128*4 l-resize weights
constexpr size_t OFF_WLI  = 25951744;            // 128*4 l-resize indices (int)
constexpr size_t OFF_WMW  = 25952256;            // 255*6 m-resize weights
constexpr size_t OFF_WMI  = 25953792;            // 255*6 m-resize indices (int)
// overlays (lifetimes disjoint):
constexpr size_t OFF_BF   = OFF_SFRE;            // fwd B frags bf16 [t][ks16][nt2][lane][8] = 8 MB (dead before legfwd writes SFRE)
constexpr size_t OFF_RRE  = OFF_FRE;             // resized flm [j'][l'][c] 255*128*32
constexpr size_t OFF_RIM  = OFF_FRE + 1044480;
constexpr size_t OFF_CRE  = OFF_FIM;             // conv out [j][l][o]
constexpr size_t OFF_CIM  = OFF_FIM + 1044480;
constexpr size_t OFF_GRE  = OFF_SFRE;            // G [t][j][c] fp32
constexpr size_t OFF_GIM  = OFF_SFRE + 2088960;
constexpr size_t OFF_BI   = OFF_FRE;             // inv B frags bf16, 8 MB (RRE/CRE dead by then)

__device__ __forceinline__ float4 ld4(const float* p) { return *(const float4*)p; }

__device__ __forceinline__ short f2bf(float f) {   // RTNE float->bf16 bits
  unsigned u = __float_as_uint(f);
  unsigned r = (u + 0x7FFFu + ((u >> 16) & 1u)) >> 16;
  return (short)r;
}

// ---------------- setup: quadrature, t_cplx, resize taps ----------------
__global__ void k_setup_small(const float* t_emb, const float* w_tr, const float* b_tr,
                              const float* w_ti, const float* b_ti, float* ws) {
  int tid = threadIdx.x;
  if (tid < 256) {
    double theta = PI_D * (2.0 * tid + 1.0) / 511.0;
    double dang = 2.0 * PI_D / 511.0;
    ws[OFF_WQ + tid] = (float)(sin(theta) * dang * dang);
  }
  if (tid < 128) {
    float sr = b_tr[tid], si = b_ti[tid];
    for (int T = 0; T < 256; ++T) {
      float e = t_emb[T];
      sr += e * w_tr[T * 128 + tid];
      si += e * w_ti[T * 128 + tid];
    }
    ws[OFF_TC + tid] = sr;
    ws[OFF_TC + 128 + tid] = si;
    double sf = 2.0 * tid + 0.5;
    double wv[4]; int iv[4]; double wsum = 0.0;
    for (int a = 0; a < 4; ++a) {
      int t = 2 * tid - 1 + a;
      double r = 1.0 - fabs(sf - (double)t) * 0.5;
      bool valid = (t >= 0 && t < 256 && r > 0.0);
      wv[a] = valid ? r : 0.0; iv[a] = valid ? t : 0;
      wsum += wv[a];
    }
    for (int a = 0; a < 4; ++a) {
      ws[OFF_WLW + tid * 4 + a] = (float)(wv[a] / wsum);
      ((int*)(ws + OFF_WLI))[tid * 4 + a] = iv[a];
    }
  }
  if (tid < 255) {
    double inv = 511.0 / 255.0;
    double sf = (tid + 0.5) * inv - 0.5;
    int t0 = (int)floor(sf) - 2;
    double wv[6]; int iv[6]; double wsum = 0.0;
    for (int b = 0; b < 6; ++b) {
      int t = t0 + b;
      double r = 1.0 - fabs(sf - (double)t) * (255.0 / 511.0);
      bool valid = (t >= 0 && t < 511 && r > 0.0);
      wv[b] = valid ? r : 0.0; iv[b] = valid ? t : 0;
      wsum += wv[b];
    }
    for (int b = 0; b < 6; ++b) {
      ws[OFF_WMW + tid * 6 + b] = (float)(wv[b] / wsum);
      ((int*)(ws + OFF_WMI))[tid * 6 + b] = iv[b];
    }
  }
}

// ---------------- premultiplied conv weights, transposed [l][o][i] ----------------
__global__ void k_wprep(const float* wr_, const float* wi_, float* ws) { // grid 512 x 256
  int gid = blockIdx.x * 256 + threadIdx.x;
  int l = gid >> 10, rem = gid & 1023, o = rem >> 5, i = rem & 31;
  float wr = wr_[(l << 10) + i * 32 + o];
  float wi = wi_[(l << 10) + i * 32 + o];
  float tcr = ws[OFF_TC + l], tci = ws[OFF_TC + 128 + l];
  ws[OFF_WPR + gid] = tcr * wr - tci * wi;
  ws[OFF_WPI + gid] = tcr * wi + tci * wr;
}

// ---------------- Legendre basis (fp64, coefficients staged in LDS) ----------------
__global__ void k_legendre(float* ws) {   // grid 256 (m) x 256 (t)
  int m = blockIdx.x, t = threadIdx.x;
  __shared__ double A[256], B[256], S[256];
  {
    int l = t;
    if (l >= 1) S[l] = -sqrt((2.0 * l + 1.0) / (2.0 * l));
    if (l >= m + 2) {
      double ll = l, mm = m;
      double den = ll * ll - mm * mm;
      A[l] = sqrt((4.0 * ll * ll - 1.0) / den);
      B[l] = sqrt((2.0 * ll + 1.0) * (ll - 1.0 - mm) * (ll - 1.0 + mm) /
                  ((2.0 * ll - 3.0) * den));
    }
  }
  __syncthreads();
  double theta = PI_D * (2.0 * t + 1.0) / 511.0;
  double ct = cos(theta), st = sin(theta);
  float* Pm = ws + OFF_P + (size_t)m * 65536 + t;
  double p0 = sqrt(1.0 / (4.0 * PI_D));
  for (int k = 1; k <= m; ++k) p0 *= S[k] * st;
  for (int l = 0; l < m; ++l) Pm[(size_t)l * 256] = 0.f;
  Pm[(size_t)m * 256] = (float)p0;
  if (m + 1 < 256) {
    double p1 = sqrt(2.0 * m + 3.0) * ct * p0;
    Pm[(size_t)(m + 1) * 256] = (float)p1;
    for (int l = m + 2; l < 256; ++l) {
      double p2 = A[l] * ct * p1 - B[l] * p0;
      Pm[(size_t)l * 256] = (float)p2;
      p0 = p1; p1 = p2;
    }
  }
}

// ---------------- A-fragment tables (bf16, MFMA A-operand layout) ----------------
// layout: [mt][ks][lane][j] ; element = A[m = mt*16 + (lane&15)][k = ks*32 + (lane>>4)*8 + j]
__global__ void k_atab_f(float* ws) { // grid 1024 x 256
  int gid = blockIdx.x * 256 + threadIdx.x;   // < 262144
  int j = gid & 7, lane = (gid >> 3) & 63, ks = (gid >> 9) & 15, mt = gid >> 13;
  int m = mt * 16 + (lane & 15);              // m' : 0..255 cos rows, 256..511 -sin rows
  int k = ks * 32 + ((lane >> 4) << 3) + j;   // phi
  float v = 0.f;
  if (k < 511) {
    int mm = (m < 256) ? m : m - 256;
    int kk = (mm * k) % 511;
    double ang = (2.0 * PI_D / 511.0) * (double)kk;
    v = (m < 256) ? (float)cos(ang) : -(float)sin(ang);
  }
  ((short*)(ws + OFF_AF))[gid] = f2bf(v);
}

__global__ void k_atab_i(float* ws) { // grid 1024 x 256
  int gid = blockIdx.x * 256 + threadIdx.x;
  int j = gid & 7, lane = (gid >> 3) & 63, ks = (gid >> 9) & 15, mt = gid >> 13;
  int m = mt * 16 + (lane & 15);              // phi: 0..510 valid
  int k = ks * 32 + ((lane >> 4) << 3) + j;   // 0..254 cos*Gre, 255..509 -sin*Gim
  float v = 0.f;
  if (m < 511 && k < 510) {
    int jj = (k < 255) ? k : k - 255;
    int jm = jj - 127;
    int kk = ((jm * m) % 511 + 511) % 511;
    double ang = (2.0 * PI_D / 511.0) * (double)kk;
    v = (k < 255) ? (float)cos(ang) : -(float)sin(ang);
  }
  ((short*)(ws + OFF_AI))[gid] = f2bf(v);
}

// ---------------- B-fragment repacks (bf16, MFMA B-operand layout) ----------------
// layout: [t][ks][nt][lane][j]; element = B[k = ks*32 + (lane>>4)*8 + j][c = nt*16 + (lane&15)]
__global__ void k_bfrag_f(const float* x, float* ws) { // grid 2048 x 256
  int gid = blockIdx.x * 256 + threadIdx.x;   // < 524288
  int lane = gid & 63, nt = (gid >> 6) & 1, ks = (gid >> 7) & 15, t = gid >> 11;
  int c = nt * 16 + (lane & 15);
  int phiB = ks * 32 + ((lane >> 4) << 3);
  float wq = ws[OFF_WQ + t];
  v8s tmp;
#pragma unroll
  for (int j = 0; j < 8; ++j) {
    int phi = phiB + j;
    tmp[j] = (phi < 511) ? f2bf(wq * x[((size_t)t * 511 + phi) * 32 + c]) : (short)0;
  }
  ((v8s*)(ws + OFF_BF))[gid] = tmp;
}

__global__ void k_bfrag_i(float* ws) { // grid 2048 x 256
  int gid = blockIdx.x * 256 + threadIdx.x;
  int lane = gid & 63, nt = (gid >> 6) & 1, ks = (gid >> 7) & 15, t = gid >> 11;
  int c = nt * 16 + (lane & 15);
  int kB = ks * 32 + ((lane >> 4) << 3);
  const float* GRE = ws + OFF_GRE;
  const float* GIM = ws + OFF_GIM;
  v8s tmp;
#pragma unroll
  for (int j = 0; j < 8; ++j) {
    int k = kB + j;
    float v = 0.f;
    if (k < 255)      v = GRE[((size_t)t * 255 + k) * 32 + c];
    else if (k < 510) v = GIM[((size_t)t * 255 + (k - 255)) * 32 + c];
    tmp[j] = f2bf(v);
  }
  ((v8s*)(ws + OFF_BI))[gid] = tmp;
}

// ---------------- MFMA GEMM: C[512][32] = A[512][512] * B[512][32] per t ----------------
// grid (nt 2, t 256) x 256; wave w handles mt = w*8..w*8+7; no LDS, fragments from global.
__global__ __launch_bounds__(256) void k_gemm_f(float* ws) {
  int nt = blockIdx.x, t = blockIdx.y;
  int tid = threadIdx.x, wave = tid >> 6, lane = tid & 63;
  const v8s* A = (const v8s*)(ws + OFF_AF);
  const v8s* B = (const v8s*)(ws + OFF_BF);
  int mtB = wave * 8;
  v4f acc[8];
#pragma unroll
  for (int i = 0; i < 8; ++i) acc[i] = (v4f){0.f, 0.f, 0.f, 0.f};
  v8s a_cur[8], b_cur, a_nxt[8], b_nxt;
  b_cur = B[(size_t)((t * 16 + 0) * 2 + nt) * 64 + lane];
#pragma unroll
  for (int i = 0; i < 8; ++i) a_cur[i] = A[(size_t)((mtB + i) * 16 + 0) * 64 + lane];
  for (int ks = 0; ks < 16; ++ks) {
    if (ks < 15) {
      b_nxt = B[(size_t)((t * 16 + ks + 1) * 2 + nt) * 64 + lane];
#pragma unroll
      for (int i = 0; i < 8; ++i) a_nxt[i] = A[(size_t)((mtB + i) * 16 + ks + 1) * 64 + lane];
    }
#pragma unroll
    for (int i = 0; i < 8; ++i)
      acc[i] = __builtin_amdgcn_mfma_f32_16x16x32_bf16(a_cur[i], b_cur, acc[i], 0, 0, 0);
    if (ks < 15) {
      b_cur = b_nxt;
#pragma unroll
      for (int i = 0; i < 8; ++i) a_cur[i] = a_nxt[i];
    }
  }
  int quad = lane >> 4, cn = nt * 16 + (lane & 15);
#pragma unroll
  for (int i = 0; i < 8; ++i) {
    int mt = mtB + i;
#pragma unroll
    for (int r = 0; r < 4; ++r) {
      int mp = mt * 16 + quad * 4 + r;
      float v = acc[i][r];
      if (mp < 256) ws[OFF_FRE + ((size_t)mp * 256 + t) * 32 + cn] = v;
      else          ws[OFF_FIM + ((size_t)(mp - 256) * 256 + t) * 32 + cn] = v;
    }
  }
}

__global__ __launch_bounds__(256) void k_gemm_i(const float* ws, float* out) {
  int nt = blockIdx.x, t = blockIdx.y;
  int tid = threadIdx.x, wave = tid >> 6, lane = tid & 63;
  const v8s* A = (const v8s*)(ws + OFF_AI);
  const v8s* B = (const v8s*)(ws + OFF_BI);
  int mtB = wave * 8;
  v4f acc[8];
#pragma unroll
  for (int i = 0; i < 8; ++i) acc[i] = (v4f){0.f, 0.f, 0.f, 0.f};
  v8s a_cur[8], b_cur, a_nxt[8], b_nxt;
  b_cur = B[(size_t)((t * 16 + 0) * 2 + nt) * 64 + lane];
#pragma unroll
  for (int i = 0; i < 8; ++i) a_cur[i] = A[(size_t)((mtB + i) * 16 + 0) * 64 + lane];
  for (int ks = 0; ks < 16; ++ks) {
    if (ks < 15) {
      b_nxt = B[(size_t)((t * 16 + ks + 1) * 2 + nt) * 64 + lane];
#pragma unroll
      for (int i = 0; i < 8; ++i) a_nxt[i] = A[(size_t)((mtB + i) * 16 + ks + 1) * 64 + lane];
    }
#pragma unroll
    for (int i = 0; i < 8; ++i)
      acc[i] = __builtin_amdgcn_mfma_f32_16x16x32_bf16(a_cur[i], b_cur, acc[i], 0, 0, 0);
    if (ks < 15) {
      b_cur = b_nxt;
#pragma unroll
      for (int i = 0; i < 8; ++i) a_cur[i] = a_nxt[i];
    }
  }
  int quad = lane >> 4, cn = nt * 16 + (lane & 15);
#pragma unroll
  for (int i = 0; i < 8; ++i) {
    int mt = mtB + i;
#pragma unroll
    for (int r = 0; r < 4; ++r) {
      int phi = mt * 16 + quad * 4 + r;
      if (phi < 511) out[((size_t)t * 511 + phi) * 32 + cn] = acc[i][r];
    }
  }
}

// ---------------- forward Legendre contraction: flm[m][l][c] ----------------
__global__ __launch_bounds__(64) void k_legfwd(float* ws) { // grid (8 ltile, 256 m) x 64
  int lt = blockIdx.x, m = blockIdx.y;
  int l0 = lt * 32;
  int tid = threadIdx.x;
  int slot = tid >> 3, cg = tid & 7;
  int c0 = cg * 4;
  float* SFRE = ws + OFF_SFRE;
  float* SFIM = ws + OFF_SFIM;
  if (l0 + 31 < m) {
#pragma unroll
    for (int k = 0; k < 4; ++k) {
      int l = l0 + slot + 8 * k;
      size_t base = ((size_t)m * 256 + l) * 32 + c0;
      *(float4*)(SFRE + base) = make_float4(0.f, 0.f, 0.f, 0.f);
      *(float4*)(SFIM + base) = make_float4(0.f, 0.f, 0.f, 0.f);
    }
    return;
  }
  __shared__ float Pl[32 * 65];
  __shared__ __align__(16) float Fre[64 * 32];
  __shared__ __align__(16) float Fim[64 * 32];
  float ar[4][4], ai[4][4];
#pragma unroll
  for (int k = 0; k < 4; ++k)
#pragma unroll
    for (int q = 0; q < 4; ++q) { ar[k][q] = 0.f; ai[k][q] = 0.f; }
  const float* Pg = ws + OFF_P + (size_t)m * 65536;
  const float* FREg = ws + OFF_FRE + (size_t)m * 8192;
  const float* FIMg = ws + OFF_FIM + (size_t)m * 8192;
  for (int ch = 0; ch < 4; ++ch) {
    int t0 = ch * 64;
    __syncthreads();
#pragma unroll
    for (int r = 0; r < 8; ++r) {
      int idx4 = tid + 64 * r;
      int ll = idx4 >> 4, t4 = (idx4 & 15) * 4;
      float4 pv = ld4(Pg + (size_t)(l0 + ll) * 256 + t0 + t4);
      float* d = Pl + ll * 65 + t4;
      d[0] = pv.x; d[1] = pv.y; d[2] = pv.z; d[3] = pv.w;
    }
#pragma unroll
    for (int r = 0; r < 8; ++r) {
      int idx4 = tid + 64 * r;
      int tt = idx4 >> 3, c4 = (idx4 & 7) * 4;
      *(float4*)(Fre + tt * 32 + c4) = ld4(FREg + (size_t)(t0 + tt) * 32 + c4);
      *(float4*)(Fim + tt * 32 + c4) = ld4(FIMg + (size_t)(t0 + tt) * 32 + c4);
    }
    __syncthreads();
    for (int tt = 0; tt < 64; ++tt) {
      float4 fr = *(const float4*)(Fre + tt * 32 + c0);
      float4 fi = *(const float4*)(Fim + tt * 32 + c0);
#pragma unroll
      for (int k = 0; k < 4; ++k) {
        float pv = Pl[(slot + 8 * k) * 65 + tt];
        ar[k][0] = fmaf(pv, fr.x, ar[k][0]); ai[k][0] = fmaf(pv, fi.x, ai[k][0]);
        ar[k][1] = fmaf(pv, fr.y, ar[k][1]); ai[k][1] = fmaf(pv, fi.y, ai[k][1]);
        ar[k][2] = fmaf(pv, fr.z, ar[k][2]); ai[k][2] = fmaf(pv, fi.z, ai[k][2]);
        ar[k][3] = fmaf(pv, fr.w, ar[k][3]); ai[k][3] = fmaf(pv, fi.w, ai[k][3]);
      }
    }
  }
#pragma unroll
  for (int k = 0; k < 4; ++k) {
    int l = l0 + slot + 8 * k;
    size_t base = ((size_t)m * 256 + l) * 32 + c0;
    *(float4*)(SFRE + base) = make_float4(ar[k][0], ar[k][1], ar[k][2], ar[k][3]);
    *(float4*)(SFIM + base) = make_float4(ai[k][0], ai[k][1], ai[k][2], ai[k][3]);
  }
}

// ---------------- bilinear (antialias) resize, fused 2-D taps ----------------
__global__ __launch_bounds__(256) void k_resize(float* ws) { // grid 4080 x 256
  int tid = threadIdx.x;
  int p = blockIdx.x * 8 + (tid >> 5);
  int c = tid & 31;
  int lp = p & 127, jp = p >> 7;
  const float* WLW = ws + OFF_WLW;
  const int* WLI = (const int*)(ws + OFF_WLI);
  const float* WMW = ws + OFF_WMW;
  const int* WMI = (const int*)(ws + OFF_WMI);
  const float* SFRE = ws + OFF_SFRE;
  const float* SFIM = ws + OFF_SFIM;
  float accr = 0.f, acci = 0.f;
  for (int b = 0; b < 6; ++b) {
    float wm = WMW[jp * 6 + b];
    int jm = WMI[jp * 6 + b];
    bool mneg = (jm < 255);
    int mm = mneg ? (255 - jm) : (jm - 255);
    float fre_f = (mneg && (mm & 1)) ? -1.f : 1.f;
    float fim_f = mneg ? -fre_f : 1.f;
#pragma unroll
    for (int a = 0; a < 4; ++a) {
      float w = wm * WLW[lp * 4 + a];
      int li = WLI[lp * 4 + a];
      size_t base = ((size_t)mm * 256 + li) * 32 + c;
      accr = fmaf(w * fre_f, SFRE[base], accr);
      acci = fmaf(w * fim_f, SFIM[base], acci);
    }
  }
  ws[OFF_RRE + ((size_t)jp * 128 + lp) * 32 + c] = accr;
  ws[OFF_RIM + ((size_t)jp * 128 + lp) * 32 + c] = acci;
}

// ---------------- per-l complex channel mix ----------------
__global__ __launch_bounds__(256) void k_conv(float* ws) { // grid (32 jg, 128 l) x 256
  int jg = blockIdx.x, l = blockIdx.y;
  int tid = threadIdx.x;
  int jl = tid >> 5, o = tid & 31;
  int j = jg * 8 + jl;
  int jc = (j < 255) ? j : 254;
  __shared__ __align__(16) float wr[32 * 36];
  __shared__ __align__(16) float wi[32 * 36];
  __shared__ __align__(16) float fr[8 * 32];
  __shared__ __align__(16) float fi[8 * 32];
  {
    int oo = tid >> 3, i4 = (tid & 7) * 4;
    *(float4*)(wr + oo * 36 + i4) = ld4(ws + OFF_WPR + ((size_t)l * 32 + oo) * 32 + i4);
    *(float4*)(wi + oo * 36 + i4) = ld4(ws + OFF_WPI + ((size_t)l * 32 + oo) * 32 + i4);
  }
  size_t fbase = ((size_t)jc * 128 + l) * 32;
  fr[jl * 32 + o] = ws[OFF_RRE + fbase + o];
  fi[jl * 32 + o] = ws[OFF_RIM + fbase + o];
  __syncthreads();
  float accr = 0.f, acci = 0.f;
#pragma unroll
  for (int i0 = 0; i0 < 32; i0 += 4) {
    float4 f_r = *(const float4*)(fr + jl * 32 + i0);
    float4 f_i = *(const float4*)(fi + jl * 32 + i0);
    float4 w_r = *(const float4*)(wr + o * 36 + i0);
    float4 w_i = *(const float4*)(wi + o * 36 + i0);
    accr += f_r.x * w_r.x - f_i.x * w_i.x;  acci += f_r.x * w_i.x + f_i.x * w_r.x;
    accr += f_r.y * w_r.y - f_i.y * w_i.y;  acci += f_r.y * w_i.y + f_i.y * w_r.y;
    accr += f_r.z * w_r.z - f_i.z * w_i.z;  acci += f_r.z * w_i.z + f_i.z * w_r.z;
    accr += f_r.w * w_r.w - f_i.w * w_i.w;  acci += f_r.w * w_i.w + f_i.w * w_r.w;
  }
  if (j < 255) {
    float s = (j < 127 && ((127 - j) & 1)) ? -1.f : 1.f;
    ws[OFF_CRE + ((size_t)j * 128 + l) * 32 + o] = s * accr;
    ws[OFF_CIM + ((size_t)j * 128 + l) * 32 + o] = s * acci;
  }
}

// ---------------- inverse Legendre: G[t][j][c] ----------------
__global__ __launch_bounds__(64) void k_leginv(float* ws) { // grid (8 ttile, 255 j) x 64
  int tt = blockIdx.x, j = blockIdx.y;
  int t0 = tt * 32;
  int tid = threadIdx.x;
  int slot = tid >> 3, cg = tid & 7;
  int c0 = cg * 4;
  int m = j - 127;
  int mm = (m < 0) ? -m : m;
  __shared__ float Pl[64 * 33];
  __shared__ __align__(16) float Cre[64 * 32];
  __shared__ __align__(16) float Cim[64 * 32];
  float ar[4][4], ai[4][4];
#pragma unroll
  for (int k = 0; k < 4; ++k)
#pragma unroll
    for (int q = 0; q < 4; ++q) { ar[k][q] = 0.f; ai[k][q] = 0.f; }
  const float* Pg = ws + OFF_P + (size_t)mm * 65536;
  const float* CREg = ws + OFF_CRE + (size_t)j * 4096;
  const float* CIMg = ws + OFF_CIM + (size_t)j * 4096;
  for (int ch = 0; ch < 2; ++ch) {
    int l0 = ch * 64;
    __syncthreads();
#pragma unroll
    for (int r = 0; r < 8; ++r) {
      int idx4 = tid + 64 * r;
      int ll = idx4 >> 3, t4 = (idx4 & 7) * 4;
      float4 pv = ld4(Pg + (size_t)(l0 + ll) * 256 + t0 + t4);
      float* d = Pl + ll * 33 + t4;
      d[0] = pv.x; d[1] = pv.y; d[2] = pv.z; d[3] = pv.w;
    }
#pragma unroll
    for (int r = 0; r < 8; ++r) {
      int idx4 = tid + 64 * r;
      int ll = idx4 >> 3, c4 = (idx4 & 7) * 4;
      *(float4*)(Cre + ll * 32 + c4) = ld4(CREg + (size_t)(l0 + ll) * 32 + c4);
      *(float4*)(Cim + ll * 32 + c4) = ld4(CIMg + (size_t)(l0 + ll) * 32 + c4);
    }
    __syncthreads();
    for (int ll = 0; ll < 64; ++ll) {
      float4 cr = *(const float4*)(Cre + ll * 32 + c0);
      float4 ci = *(const float4*)(Cim + ll * 32 + c0);
#pragma unroll
      for (int k = 0; k < 4; ++k) {
        float pv = Pl[ll * 33 + slot + 8 * k];
        ar[k][0] = fmaf(pv, cr.x, ar[k][0]); ai[k][0] = fmaf(pv, ci.x, ai[k][0]);
        ar[k][1] = fmaf(pv, cr.y, ar[k][1]); ai[k][1] = fmaf(pv, ci.y, ai[k][1]);
        ar[k][2] = fmaf(pv, cr.z, ar[k][2]); ai[k][2] = fmaf(pv, ci.z, ai[k][2]);
        ar[k][3] = fmaf(pv, cr.w, ar[k][3]); ai[k][3] = fmaf(pv, ci.w, ai[k][3]);
      }
    }
  }
#pragma unroll
  for (int k = 0; k < 4; ++k) {
    int tloc = t0 + slot + 8 * k;
    size_t base = ((size_t)tloc * 255 + j) * 32 + c0;
    *(float4*)(ws + OFF_GRE + base) = make_float4(ar[k][0], ar[k][1], ar[k][2], ar[k][3]);
    *(float4*)(ws + OFF_GIM + base) = make_float4(ai[k][0], ai[k][1], ai[k][2], ai[k][3]);
  }
}

// ---------------- launch ----------------
extern "C" void kernel_launch(void* const* d_in, const int* in_sizes, int n_in,
                              void* d_out, int out_size, void* d_ws, size_t ws_size,
                              hipStream_t stream) {
  const float* x = (const float*)d_in[0];
  const float* t_emb = (const float*)d_in[1];
  const float* w_real = (const float*)d_in[2];
  const float* w_imag = (const float*)d_in[3];
  const float* w_tr = (const float*)d_in[4];
  const float* b_tr = (const float*)d_in[5];
  const float* w_ti = (const float*)d_in[6];
  const float* b_ti = (const float*)d_in[7];
  float* ws = (float*)d_ws;
  float* out = (float*)d_out;
  (void)in_sizes; (void)n_in; (void)out_size; (void)ws_size;

  hipLaunchKernelGGL(k_setup_small, dim3(1), dim3(256), 0, stream,
                     t_emb, w_tr, b_tr, w_ti, b_ti, ws);
  hipLaunchKernelGGL(k_wprep, dim3(512), dim3(256), 0, stream, w_real, w_imag, ws);
  hipLaunchKernelGGL(k_legendre, dim3(256), dim3(256), 0, stream, ws);
  hipLaunchKernelGGL(k_atab_f, dim3(1024), dim3(256), 0, stream, ws);
  hipLaunchKernelGGL(k_atab_i, dim3(1024), dim3(256), 0, stream, ws);
  hipLaunchKernelGGL(k_bfrag_f, dim3(2048), dim3(256), 0, stream, x, ws);
  hipLaunchKernelGGL(k_gemm_f, dim3(2, 256), dim3(256), 0, stream, ws);
  hipLaunchKernelGGL(k_legfwd, dim3(8, 256), dim3(64), 0, stream, ws);
  hipLaunchKernelGGL(k_resize, dim3(4080), dim3(256), 0, stream, ws);
  hipLaunchKernelGGL(k_conv, dim3(32, 128), dim3(256), 0, stream, ws);
  hipLaunchKernelGGL(k_leginv, dim3(8, 255), dim3(64), 0, stream, ws);
  hipLaunchKernelGGL(k_bfrag_i, dim3(2048), dim3(256), 0, stream, ws);
  hipLaunchKernelGGL(k_gemm_i, dim3(2, 256), dim3(256), 0, stream, ws, out);
}